// Round 10
// baseline (216.354 us; speedup 1.0000x reference)
//
#include <hip/hip_runtime.h>
#include <hip/hip_bf16.h>
#include <math.h>

#define HDIM 100
#define NFACT 262144
#define FPB   256             // facts per block
#define NBLK  1024            // NFACT / FPB
#define NTHREADS 1024         // 16 waves; wave w owns facts [w*16, w*16+16), ALL j

// K packed to 256: k in [0,128) -> (f - oc) (valid k<100), k in [128,256) -> (f - m).
// Dead k ranges have W1-frag == 0 and z == 0.
#define NJT 7                 // j-tiles of 16 (112 >= 100)
#define NKC 8
#define NBFRAG (NJT * NKC * 64)   // 3584 uint4

#define NCOPY 104             // accumulator copy stride: corr[100] + S at [100]

using short8 = __attribute__((ext_vector_type(8))) short;
using f32x4  = __attribute__((ext_vector_type(4))) float;

// ---------------- ws float-offset layout ----------------
#define WS_B    0                 // 14336 floats (3584 uint4 W1-fragments, bf16 bits)
#define WS_ACC  14336             // 32 copies x 104 floats (zeroed by k_prep_b)

__device__ __forceinline__ unsigned short f2bf(float x) {
    unsigned u = __builtin_bit_cast(unsigned, x);
    u += 0x7FFFu + ((u >> 16) & 1u);          // RNE round to bf16
    return (unsigned short)(u >> 16);
}

__device__ __forceinline__ float tanh_fast(float x) {
    float e = __expf(2.0f * x);
    return 1.0f - 2.0f / (1.0f + e);
}

// ---- Precompute W1 fragments (bf16), order [jt][kc][lane][8]; zero accumulators ----
// MFMA A operand: A[row=j][k]; per lane: j = jt*16 + (lane&15), k = kc*32 + (lane>>4)*8 + e.
__global__ __launch_bounds__(256) void k_prep_b(const float* __restrict__ W1,
                                                float* __restrict__ ws) {
    int tg = blockIdx.x * 256 + threadIdx.x;
    if (tg < 32 * NCOPY) ws[WS_ACC + tg] = 0.f;   // zero all accumulator copies
    if (tg >= NBFRAG) return;
    int lane = tg & 63;
    int kc = (tg >> 6) & 7;
    int jt = tg >> 9;
    int g = lane >> 4, r = lane & 15;
    int j = jt * 16 + r;
    unsigned short v[8];
    #pragma unroll
    for (int e = 0; e < 8; e++) {
        int kglob = kc * 32 + g * 8 + e;
        int half = kglob >> 7;
        int koff = kglob & 127;
        float x = 0.f;
        if (j < HDIM && koff < HDIM) x = W1[j * 200 + half * HDIM + koff];
        v[e] = f2bf(x);
    }
    uint4 d;
    d.x = (unsigned)v[0] | ((unsigned)v[1] << 16);
    d.y = (unsigned)v[2] | ((unsigned)v[3] << 16);
    d.z = (unsigned)v[4] | ((unsigned)v[5] << 16);
    d.w = (unsigned)v[6] | ((unsigned)v[7] << 16);
    ((uint4*)(ws + WS_B))[tg] = d;
}

__device__ __forceinline__ float4 ld4c(const float* p, bool ok) {
    float4 z = make_float4(0.f, 0.f, 0.f, 0.f);
    return ok ? *(const float4*)p : z;
}

__device__ __forceinline__ short8 pack_diff(float4 a0, float4 a1,
                                            float4 b0, float4 b1) {
    union { __hip_bfloat16 h[8]; short8 v; } u;
    u.h[0] = __float2bfloat16(a0.x - b0.x); u.h[1] = __float2bfloat16(a0.y - b0.y);
    u.h[2] = __float2bfloat16(a0.z - b0.z); u.h[3] = __float2bfloat16(a0.w - b0.w);
    u.h[4] = __float2bfloat16(a1.x - b1.x); u.h[5] = __float2bfloat16(a1.y - b1.y);
    u.h[6] = __float2bfloat16(a1.z - b1.z); u.h[7] = __float2bfloat16(a1.w - b1.w);
    return u.v;
}

// DPP row-rotate add (VALU pipe): x + rotate_within_16(x, N)
template<int CTRL>
__device__ __forceinline__ float dpp_radd(float x) {
    int y = __builtin_amdgcn_update_dpp(0, __builtin_bit_cast(int, x),
                                        CTRL, 0xF, 0xF, true);
    return x + __builtin_bit_cast(float, y);
}
__device__ __forceinline__ float row_reduce16(float x) {
    x = dpp_radd<0x121>(x);   // row_ror:1
    x = dpp_radd<0x122>(x);   // row_ror:2
    x = dpp_radd<0x124>(x);   // row_ror:4
    x = dpp_radd<0x128>(x);   // row_ror:8
    return x;                 // all 16 lanes of the row hold the row-sum
}

#define P2S 36                // pool2 slice stride (floats): 144 B, 16B-aligned

// One wave = 16 facts, all j, everything in-wave. 16 waves/block, 2 barriers.
__global__ __launch_bounds__(NTHREADS, 8) void k_logits(
        const float* __restrict__ fe,
        const float* __restrict__ oc,
        const float* __restrict__ mvec,
        const float* __restrict__ b1,
        const float* __restrict__ W2,
        float* __restrict__ ws) {
    __shared__ uint4 Bs[NBFRAG];              // 57344 B (W1 fragments)
    __shared__ float pool2[64 * P2S];         // (w*4+c)*P2S + g*8+e  — 9216 B
    __shared__ float sS;

    int t = threadIdx.x;
    int w = t >> 6, lane = t & 63, g = lane >> 4, r = lane & 15;
    long n0 = (long)blockIdx.x * FPB;

    if (t == 0) sS = 0.f;

    // ---- stage W1 table -> LDS (coalesced, L2/L3-hot) ----
    {
        const uint4* Bg = (const uint4*)(ws + WS_B);
        #pragma unroll
        for (int i = 0; i < 4; i++) {
            int idx = t + i * 1024;
            if (idx < NBFRAG) Bs[idx] = Bg[idx];
        }
    }

    // ---- this lane's fact-row loads (cols c*32+g*8 .. +8) ----
    const float* fp = fe + (n0 + w * 16 + r) * HDIM;
    float4 fa[4], fb[4], oa[4], ob[4], ma[4], mb[4];
    #pragma unroll
    for (int c = 0; c < 4; c++) {
        int base = c * 32 + g * 8;
        bool v0 = base < HDIM, v1 = base + 4 < HDIM;
        fa[c] = ld4c(fp + base, v0);   fb[c] = ld4c(fp + base + 4, v1);
        oa[c] = ld4c(oc + base, v0);   ob[c] = ld4c(oc + base + 4, v1);
        ma[c] = ld4c(mvec + base, v0); mb[c] = ld4c(mvec + base + 4, v1);
    }

    // ---- signed z (bf16): zoc = f-oc (pooling + k<128); zabs = |z| for MFMA ----
    short8 zoc[4];
    uint4 zabs[8];
    #pragma unroll
    for (int c = 0; c < 4; c++) {
        zoc[c] = pack_diff(fa[c], fb[c], oa[c], ob[c]);
        uint4 u = __builtin_bit_cast(uint4, zoc[c]);
        u.x &= 0x7FFF7FFFu; u.y &= 0x7FFF7FFFu; u.z &= 0x7FFF7FFFu; u.w &= 0x7FFF7FFFu;
        zabs[c] = u;
        short8 zm = pack_diff(fa[c], fb[c], ma[c], mb[c]);
        uint4 v = __builtin_bit_cast(uint4, zm);
        v.x &= 0x7FFF7FFFu; v.y &= 0x7FFF7FFFu; v.z &= 0x7FFF7FFFu; v.w &= 0x7FFF7FFFu;
        zabs[4 + c] = v;
    }
    __syncthreads();

    // ---- GEMM: C[j][fact] = mfma(W1frag, zabs); C col = r = my fact ----
    float gacc = 0.f;
    #pragma unroll
    for (int jt = 0; jt < NJT; jt++) {
        f32x4 acc = {0, 0, 0, 0};
        #pragma unroll
        for (int kc = 0; kc < NKC; kc++) {
            short8 av = __builtin_bit_cast(short8, Bs[(jt * 8 + kc) * 64 + lane]);
            acc = __builtin_amdgcn_mfma_f32_16x16x32_bf16(
                av, __builtin_bit_cast(short8, zabs[kc]), acc, 0, 0, 0);
        }
        #pragma unroll
        for (int q = 0; q < 4; q++) {
            int j = jt * 16 + g * 4 + q;
            float w2j = (j < HDIM) ? W2[j] : 0.f;
            float b1j = (j < HDIM) ? b1[j] : 0.f;
            gacc = fmaf(tanh_fast(acc[q] + b1j), w2j, gacc);
        }
    }
    // sum partial logits over the 4 g-groups -> logit of fact (n0 + w*16 + r)
    gacc += __shfl_xor(gacc, 16);
    gacc += __shfl_xor(gacc, 32);
    float w_r = __expf(gacc);     // b2 dropped (softmax-invariant); |logit| <= sum|W2| ~ 8

    // ---- S partial: sum w_r over r (DPP), one LDS atomic per wave ----
    float s16 = row_reduce16(w_r);
    if (lane == 0) atomicAdd(&sS, s16);

    // ---- pooling from z regs: p[k] = sum_r w_r * (f-oc)[r][k], k = c*32+g*8+e ----
    float p[4][8];
    #pragma unroll
    for (int c = 0; c < 4; c++) {
        union { short8 v; unsigned short us[8]; } uz; uz.v = zoc[c];
        #pragma unroll
        for (int e = 0; e < 8; e++) {
            float zf = __builtin_bit_cast(float, ((unsigned)uz.us[e]) << 16);
            p[c][e] = w_r * zf;
        }
    }
    #pragma unroll
    for (int c = 0; c < 4; c++)
        #pragma unroll
        for (int e = 0; e < 8; e++) p[c][e] = row_reduce16(p[c][e]);

    if (r == 0) {   // 4 g-lanes write their 32 k-slots, conflict-free, 16B-aligned
        #pragma unroll
        for (int c = 0; c < 4; c++) {
            float* dst = pool2 + (w * 4 + c) * P2S + g * 8;
            *(float4*)(dst)     = make_float4(p[c][0], p[c][1], p[c][2], p[c][3]);
            *(float4*)(dst + 4) = make_float4(p[c][4], p[c][5], p[c][6], p[c][7]);
        }
    }
    __syncthreads();

    // ---- block flush -> striped accumulator copy (blockIdx & 31) ----
    int cp = (blockIdx.x & 31) * NCOPY;
    if (t < 128) {
        int c = t >> 5, off = t & 31;             // k = c*32 + off
        float a = 0.f;
        #pragma unroll
        for (int w16 = 0; w16 < 16; w16++) a += pool2[(w16 * 4 + c) * P2S + off];
        if (t < HDIM) atomicAdd(&ws[WS_ACC + cp + t], a);
    }
    if (t == 0) atomicAdd(&ws[WS_ACC + cp + HDIM], sS);
}

// Tiny epilogue: c = oc + corr/S; gated update. One block.
__global__ __launch_bounds__(128) void k_final(
        const float* __restrict__ mvec,
        const float* __restrict__ oc,
        const float* __restrict__ W3,
        const float* __restrict__ b3,
        const float* __restrict__ ws,
        float* __restrict__ out) {
    __shared__ float vv[300];
    int t = threadIdx.x;
    float S = 0.f;
    #pragma unroll
    for (int i = 0; i < 32; i++) S += ws[WS_ACC + i * NCOPY + HDIM];
    if (t < HDIM) {
        float corr = 0.f;
        #pragma unroll
        for (int i = 0; i < 32; i++) corr += ws[WS_ACC + i * NCOPY + t];
        vv[t] = mvec[t];
        vv[HDIM + t] = oc[t] + corr / S;
        vv[2 * HDIM + t] = oc[t];
    }
    __syncthreads();
    if (t < HDIM) {
        float a = b3[t];
        const float* wr = W3 + t * 3 * HDIM;
        #pragma unroll 4
        for (int k = 0; k < 3 * HDIM; k++) a = fmaf(wr[k], vv[k], a);
        out[t] = fmaxf(a, 0.f);
    }
}

extern "C" void kernel_launch(void* const* d_in, const int* in_sizes, int n_in,
                              void* d_out, int out_size, void* d_ws, size_t ws_size,
                              hipStream_t stream) {
    const float* mvec = (const float*)d_in[0];
    const float* oh   = (const float*)d_in[1];
    const float* fe   = (const float*)d_in[2];
    const float* W1   = (const float*)d_in[3];
    const float* b1   = (const float*)d_in[4];
    const float* W2   = (const float*)d_in[5];
    const float* W3   = (const float*)d_in[7];
    const float* b3   = (const float*)d_in[8];
    float* ws  = (float*)d_ws;
    float* out = (float*)d_out;

    k_prep_b<<<14, 256, 0, stream>>>(W1, ws);
    k_logits<<<NBLK, NTHREADS, 0, stream>>>(fe, oh, mvec, b1, W2, ws);
    k_final<<<1, 128, 0, stream>>>(mvec, oh, W3, b3, ws, out);
}

// Round 11
// 192.424 us; speedup vs baseline: 1.1244x; 1.1244x over previous
//
#include <hip/hip_runtime.h>
#include <hip/hip_bf16.h>
#include <math.h>

#define HDIM 100
#define NFACT 262144
#define FPB   128             // facts per block (8 waves x 16)
#define NBLK  2048            // NFACT / FPB
#define NTHREADS 512

// K packed to 224: k in [0,112) -> (f - oc) (valid k<100), k in [112,224) -> (f - m)
// (valid k-112<100). Dead k ranges have W1-frag == 0 and z == 0. 112 % 8 == 0 so no
// 8-element MFMA k-group straddles the boundary.
#define KHALF 112
#define NJT 7                 // j-tiles of 16 (112 >= 100)
#define NKC 7                 // k-chunks of 32 (224)
#define NBFRAG (NJT * NKC * 64)   // 3136 uint4 = 50176 B

#define NCOPY 116             // accumulator stripe: corr[112] + S at [112]
#define NSTRIPE 32

using short8 = __attribute__((ext_vector_type(8))) short;
using f32x4  = __attribute__((ext_vector_type(4))) float;

// ---------------- ws float-offset layout ----------------
#define WS_B    0                 // 12544 floats (3136 uint4 W1-fragments, bf16 bits)
#define WS_ACC  12544             // 32 stripes x 116 floats (zeroed by k_prep_b)

__device__ __forceinline__ unsigned short f2bf(float x) {
    unsigned u = __builtin_bit_cast(unsigned, x);
    u += 0x7FFFu + ((u >> 16) & 1u);          // RNE round to bf16
    return (unsigned short)(u >> 16);
}

__device__ __forceinline__ float tanh_fast(float x) {
    float e = __expf(2.0f * x);
    return 1.0f - 2.0f / (1.0f + e);
}

// ---- Precompute W1 fragments (bf16), order [jt][kc][lane][8]; zero accumulators ----
// MFMA A operand: A[row=j][k]; per lane: j = jt*16 + (lane&15), k = kc*32 + (lane>>4)*8 + e.
__global__ __launch_bounds__(256) void k_prep_b(const float* __restrict__ W1,
                                                float* __restrict__ ws) {
    int tg = blockIdx.x * 256 + threadIdx.x;
    if (tg < NSTRIPE * NCOPY) ws[WS_ACC + tg] = 0.f;   // zero all stripes each call
    if (tg >= NBFRAG) return;
    int lane = tg & 63;
    int kc = (tg >> 6) % NKC;
    int jt = tg / (NKC * 64);
    int g = lane >> 4, r = lane & 15;
    int j = jt * 16 + r;
    unsigned short v[8];
    #pragma unroll
    for (int e = 0; e < 8; e++) {
        int kglob = kc * 32 + g * 8 + e;
        int half = (kglob >= KHALF) ? 1 : 0;
        int koff = kglob - half * KHALF;
        float x = 0.f;
        if (j < HDIM && koff < HDIM) x = W1[j * 200 + half * HDIM + koff];
        v[e] = f2bf(x);
    }
    uint4 d;
    d.x = (unsigned)v[0] | ((unsigned)v[1] << 16);
    d.y = (unsigned)v[2] | ((unsigned)v[3] << 16);
    d.z = (unsigned)v[4] | ((unsigned)v[5] << 16);
    d.w = (unsigned)v[6] | ((unsigned)v[7] << 16);
    ((uint4*)(ws + WS_B))[tg] = d;
}

__device__ __forceinline__ float4 ld4c(const float* p, bool ok) {
    float4 z = make_float4(0.f, 0.f, 0.f, 0.f);
    return ok ? *(const float4*)p : z;
}

__device__ __forceinline__ uint4 pack_diff_u(float4 a0, float4 a1,
                                             float4 b0, float4 b1) {
    union { __hip_bfloat16 h[8]; uint4 u; } u;
    u.h[0] = __float2bfloat16(a0.x - b0.x); u.h[1] = __float2bfloat16(a0.y - b0.y);
    u.h[2] = __float2bfloat16(a0.z - b0.z); u.h[3] = __float2bfloat16(a0.w - b0.w);
    u.h[4] = __float2bfloat16(a1.x - b1.x); u.h[5] = __float2bfloat16(a1.y - b1.y);
    u.h[6] = __float2bfloat16(a1.z - b1.z); u.h[7] = __float2bfloat16(a1.w - b1.w);
    return u.u;
}

// DPP row-rotate add (VALU pipe): x + rotate_within_16(x, N)
template<int CTRL>
__device__ __forceinline__ float dpp_radd(float x) {
    int y = __builtin_amdgcn_update_dpp(0, __builtin_bit_cast(int, x),
                                        CTRL, 0xF, 0xF, true);
    return x + __builtin_bit_cast(float, y);
}
__device__ __forceinline__ float row_reduce16(float x) {
    x = dpp_radd<0x121>(x);   // row_ror:1
    x = dpp_radd<0x122>(x);   // row_ror:2
    x = dpp_radd<0x124>(x);   // row_ror:4
    x = dpp_radd<0x128>(x);   // row_ror:8
    return x;                 // all 16 lanes of the row hold the row-sum
}

// One wave = 16 facts, all j. W1 table async-staged to LDS; pooling buffer
// ALIASES the W1 LDS after a post-GEMM barrier -> 50.2 KB LDS -> 3 blocks/CU.
__global__ __launch_bounds__(NTHREADS, 6) void k_logits(
        const float* __restrict__ fe,
        const float* __restrict__ oc,
        const float* __restrict__ mvec,
        const float* __restrict__ b1,
        const float* __restrict__ W2,
        float* __restrict__ ws) {
    __shared__ __align__(16) char smem[NBFRAG * 16];   // 50176 B
    __shared__ float sS;
    uint4* Bs = (uint4*)smem;
    float* pool2 = (float*)smem;    // reused AFTER the post-GEMM barrier

    int t = threadIdx.x;
    int w = t >> 6, lane = t & 63, g = lane >> 4, r = lane & 15;
    long n0 = (long)blockIdx.x * FPB;

    if (t == 0) sS = 0.f;

    // ---- async stage W1 table: global -> LDS, width 16, linear layout ----
    {
        const uint4* Bg = (const uint4*)(ws + WS_B);
        #pragma unroll
        for (int i = 0; i < 7; i++) {
            int base = i * 512 + w * 64;          // wave-uniform
            if (base < NBFRAG) {
                __builtin_amdgcn_global_load_lds(
                    (const __attribute__((address_space(1))) unsigned int*)(Bg + base + lane),
                    (__attribute__((address_space(3))) unsigned int*)(Bs + base),
                    16, 0, 0);
            }
        }
    }

    // ---- per-lane f loads + z build (runs while W1 staging is in flight) ----
    const float* fp = fe + (n0 + w * 16 + r) * HDIM;
    uint4 zabs[NKC];
    uint4 zsig[4];                 // signed chunks kc=0..3 (pooling, oc-half)
    #pragma unroll
    for (int kc = 0; kc < NKC; kc++) {
        int pk = kc * 32 + g * 8;
        int hlf = (pk >= KHALF) ? 1 : 0;
        int col = pk - hlf * KHALF;
        const float* sp = hlf ? mvec : oc;
        bool v0 = col < HDIM, v1 = col + 4 < HDIM;
        float4 f0 = ld4c(fp + col, v0), f1 = ld4c(fp + col + 4, v1);
        float4 s0 = ld4c(sp + col, v0), s1 = ld4c(sp + col + 4, v1);
        uint4 u = pack_diff_u(f0, f1, s0, s1);
        if (kc < 4) zsig[kc] = u;
        u.x &= 0x7FFF7FFFu; u.y &= 0x7FFF7FFFu; u.z &= 0x7FFF7FFFu; u.w &= 0x7FFF7FFFu;
        zabs[kc] = u;
    }
    __syncthreads();   // drains vmcnt -> Bs ready

    // ---- GEMM: C[j][fact] = mfma(W1frag, |z|); C col = r = my fact; b1 in C-init ----
    float gacc = 0.f;
    #pragma unroll
    for (int jt = 0; jt < NJT; jt++) {
        int jb = jt * 16 + g * 4;
        bool jv = jb < HDIM;                       // group fully valid or fully dead
        float4 b1q = ld4c(b1 + jb, jv);
        float4 w2q = ld4c(W2 + jb, jv);
        f32x4 acc = {b1q.x, b1q.y, b1q.z, b1q.w};
        #pragma unroll
        for (int kc = 0; kc < NKC; kc++) {
            short8 av = __builtin_bit_cast(short8, Bs[(jt * NKC + kc) * 64 + lane]);
            acc = __builtin_amdgcn_mfma_f32_16x16x32_bf16(
                av, __builtin_bit_cast(short8, zabs[kc]), acc, 0, 0, 0);
        }
        gacc = fmaf(tanh_fast(acc[0]), w2q.x, gacc);
        gacc = fmaf(tanh_fast(acc[1]), w2q.y, gacc);
        gacc = fmaf(tanh_fast(acc[2]), w2q.z, gacc);
        gacc = fmaf(tanh_fast(acc[3]), w2q.w, gacc);
    }
    // combine the 4 g-group partials -> logit of fact (n0 + w*16 + r)
    gacc += __shfl_xor(gacc, 16);
    gacc += __shfl_xor(gacc, 32);
    float w_r = __expf(gacc);      // b2 dropped (softmax-invariant); |logit| <= sum|W2| ~ 8

    float s16 = row_reduce16(w_r);
    if (lane == 0) atomicAdd(&sS, s16);

    // ---- pooling from signed z regs: p[k] = sum_r w_r*(f-oc)[r][k] (oc-half only) ----
    float p[4][8];
    #pragma unroll
    for (int c = 0; c < 4; c++) {
        union { uint4 u; unsigned short us[8]; } uz; uz.u = zsig[c];
        #pragma unroll
        for (int e = 0; e < 8; e++) {
            float zf = __builtin_bit_cast(float, ((unsigned)uz.us[e]) << 16);
            p[c][e] = w_r * zf;
        }
    }
    #pragma unroll
    for (int c = 0; c < 4; c++)
        #pragma unroll
        for (int e = 0; e < 8; e++) p[c][e] = row_reduce16(p[c][e]);

    __syncthreads();   // ALL waves done reading Bs -> safe to alias pool2

    if (r == 0) {      // lanes g=0..3 write their oc-half slots (pk<112)
        #pragma unroll
        for (int c = 0; c < 4; c++) {
            int pk = c * 32 + g * 8;
            if (pk < KHALF) {
                float* dst = pool2 + w * KHALF + pk;
                *(float4*)(dst)     = make_float4(p[c][0], p[c][1], p[c][2], p[c][3]);
                *(float4*)(dst + 4) = make_float4(p[c][4], p[c][5], p[c][6], p[c][7]);
            }
        }
    }
    __syncthreads();

    // ---- block flush -> striped global accumulator ----
    int cp = (blockIdx.x & (NSTRIPE - 1)) * NCOPY;
    if (t < KHALF) {
        float a = 0.f;
        #pragma unroll
        for (int w8 = 0; w8 < 8; w8++) a += pool2[w8 * KHALF + t];
        if (t < HDIM) atomicAdd(&ws[WS_ACC + cp + t], a);
    }
    if (t == 0) atomicAdd(&ws[WS_ACC + cp + KHALF], sS);
}

// Tiny epilogue: c = oc + corr/S; gated update. One block.
__global__ __launch_bounds__(128) void k_final(
        const float* __restrict__ mvec,
        const float* __restrict__ oc,
        const float* __restrict__ W3,
        const float* __restrict__ b3,
        const float* __restrict__ ws,
        float* __restrict__ out) {
    __shared__ float vv[300];
    int t = threadIdx.x;
    float S = 0.f;
    #pragma unroll
    for (int i = 0; i < NSTRIPE; i++) S += ws[WS_ACC + i * NCOPY + KHALF];
    if (t < HDIM) {
        float corr = 0.f;
        #pragma unroll
        for (int i = 0; i < NSTRIPE; i++) corr += ws[WS_ACC + i * NCOPY + t];
        vv[t] = mvec[t];
        vv[HDIM + t] = oc[t] + corr / S;
        vv[2 * HDIM + t] = oc[t];
    }
    __syncthreads();
    if (t < HDIM) {
        float a = b3[t];
        const float* wr = W3 + t * 3 * HDIM;
        #pragma unroll 4
        for (int k = 0; k < 3 * HDIM; k++) a = fmaf(wr[k], vv[k], a);
        out[t] = fmaxf(a, 0.f);
    }
}

extern "C" void kernel_launch(void* const* d_in, const int* in_sizes, int n_in,
                              void* d_out, int out_size, void* d_ws, size_t ws_size,
                              hipStream_t stream) {
    const float* mvec = (const float*)d_in[0];
    const float* oh   = (const float*)d_in[1];
    const float* fe   = (const float*)d_in[2];
    const float* W1   = (const float*)d_in[3];
    const float* b1   = (const float*)d_in[4];
    const float* W2   = (const float*)d_in[5];
    const float* W3   = (const float*)d_in[7];
    const float* b3   = (const float*)d_in[8];
    float* ws  = (float*)d_ws;
    float* out = (float*)d_out;

    k_prep_b<<<15, 256, 0, stream>>>(W1, ws);
    k_logits<<<NBLK, NTHREADS, 0, stream>>>(fe, oh, mvec, b1, W2, ws);
    k_final<<<1, 128, 0, stream>>>(mvec, oh, W3, b3, ws, out);
}

// Round 12
// 93.447 us; speedup vs baseline: 2.3153x; 2.0592x over previous
//
#include <hip/hip_runtime.h>
#include <hip/hip_bf16.h>
#include <math.h>

#define HDIM 100
#define NFACT 262144
#define FPB   128             // facts per block (8 waves x 16)
#define NBLK  2048            // NFACT / FPB
#define NTHREADS 512

// K packed to 224: k in [0,112) -> (f - oc) (valid k<100), k in [112,224) -> (f - m)
// (valid k-112<100). Dead k ranges have W1-frag == 0 and z == 0. 112 % 8 == 0 so no
// 8-element MFMA k-group straddles the boundary.
#define KHALF 112
#define NJT 7                 // j-tiles of 16 (112 >= 100)
#define NKC 7                 // k-chunks of 32 (224)
#define NBFRAG (NJT * NKC * 64)   // 3136 uint4 = 50176 B

#define NCOPY 116             // accumulator stripe: corr[112] + S at [112]
#define NSTRIPE 32

using short8 = __attribute__((ext_vector_type(8))) short;
using f32x4  = __attribute__((ext_vector_type(4))) float;

// ---------------- ws float-offset layout ----------------
#define WS_B    0                 // 12544 floats (3136 uint4 W1-fragments, bf16 bits)
#define WS_ACC  12544             // 32 stripes x 116 floats (zeroed by k_prep_b)

__device__ __forceinline__ unsigned short f2bf(float x) {
    unsigned u = __builtin_bit_cast(unsigned, x);
    u += 0x7FFFu + ((u >> 16) & 1u);          // RNE round to bf16
    return (unsigned short)(u >> 16);
}

__device__ __forceinline__ float tanh_fast(float x) {
    float e = __expf(2.0f * x);
    return 1.0f - 2.0f / (1.0f + e);
}

// ---- Precompute W1 fragments (bf16), order [jt][kc][lane][8]; zero accumulators ----
// MFMA A operand: A[row=j][k]; per lane: j = jt*16 + (lane&15), k = kc*32 + (lane>>4)*8 + e.
__global__ __launch_bounds__(256) void k_prep_b(const float* __restrict__ W1,
                                                float* __restrict__ ws) {
    int tg = blockIdx.x * 256 + threadIdx.x;
    if (tg < NSTRIPE * NCOPY) ws[WS_ACC + tg] = 0.f;   // zero all stripes each call
    if (tg >= NBFRAG) return;
    int lane = tg & 63;
    int kc = (tg >> 6) % NKC;
    int jt = tg / (NKC * 64);
    int g = lane >> 4, r = lane & 15;
    int j = jt * 16 + r;
    unsigned short v[8];
    #pragma unroll
    for (int e = 0; e < 8; e++) {
        int kglob = kc * 32 + g * 8 + e;
        int half = (kglob >= KHALF) ? 1 : 0;
        int koff = kglob - half * KHALF;
        float x = 0.f;
        if (j < HDIM && koff < HDIM) x = W1[j * 200 + half * HDIM + koff];
        v[e] = f2bf(x);
    }
    uint4 d;
    d.x = (unsigned)v[0] | ((unsigned)v[1] << 16);
    d.y = (unsigned)v[2] | ((unsigned)v[3] << 16);
    d.z = (unsigned)v[4] | ((unsigned)v[5] << 16);
    d.w = (unsigned)v[6] | ((unsigned)v[7] << 16);
    ((uint4*)(ws + WS_B))[tg] = d;
}

__device__ __forceinline__ float4 ld4c(const float* p, bool ok) {
    float4 z = make_float4(0.f, 0.f, 0.f, 0.f);
    return ok ? *(const float4*)p : z;
}

__device__ __forceinline__ uint4 pack_diff_u(float4 a0, float4 a1,
                                             float4 b0, float4 b1) {
    union { __hip_bfloat16 h[8]; uint4 u; } u;
    u.h[0] = __float2bfloat16(a0.x - b0.x); u.h[1] = __float2bfloat16(a0.y - b0.y);
    u.h[2] = __float2bfloat16(a0.z - b0.z); u.h[3] = __float2bfloat16(a0.w - b0.w);
    u.h[4] = __float2bfloat16(a1.x - b1.x); u.h[5] = __float2bfloat16(a1.y - b1.y);
    u.h[6] = __float2bfloat16(a1.z - b1.z); u.h[7] = __float2bfloat16(a1.w - b1.w);
    return u.u;
}

// DPP row-rotate add (VALU pipe): x + rotate_within_16(x, N)
template<int CTRL>
__device__ __forceinline__ float dpp_radd(float x) {
    int y = __builtin_amdgcn_update_dpp(0, __builtin_bit_cast(int, x),
                                        CTRL, 0xF, 0xF, true);
    return x + __builtin_bit_cast(float, y);
}
__device__ __forceinline__ float row_reduce16(float x) {
    x = dpp_radd<0x121>(x);   // row_ror:1
    x = dpp_radd<0x122>(x);   // row_ror:2
    x = dpp_radd<0x124>(x);   // row_ror:4
    x = dpp_radd<0x128>(x);   // row_ror:8
    return x;                 // all 16 lanes of the row hold the row-sum
}

// One wave = 16 facts, all j. W1 table async-staged to LDS; pooling buffer
// ALIASES the W1 LDS after a post-GEMM barrier -> 50.2 KB LDS -> 3 blocks/CU.
// launch_bounds min-wave = 4 (NOT 6/8): higher values cap VGPR and spill (R10/R11).
__global__ __launch_bounds__(NTHREADS, 4) void k_logits(
        const float* __restrict__ fe,
        const float* __restrict__ oc,
        const float* __restrict__ mvec,
        const float* __restrict__ b1,
        const float* __restrict__ W2,
        float* __restrict__ ws) {
    __shared__ __align__(16) char smem[NBFRAG * 16];   // 50176 B
    __shared__ float sS;
    uint4* Bs = (uint4*)smem;
    float* pool2 = (float*)smem;    // reused AFTER the post-GEMM barrier

    int t = threadIdx.x;
    int w = t >> 6, lane = t & 63, g = lane >> 4, r = lane & 15;
    long n0 = (long)blockIdx.x * FPB;

    if (t == 0) sS = 0.f;

    // ---- async stage W1 table: global -> LDS, width 16, linear layout ----
    {
        const uint4* Bg = (const uint4*)(ws + WS_B);
        #pragma unroll
        for (int i = 0; i < 7; i++) {
            int base = i * 512 + w * 64;          // wave-uniform
            if (base < NBFRAG) {
                __builtin_amdgcn_global_load_lds(
                    (const __attribute__((address_space(1))) unsigned int*)(Bg + base + lane),
                    (__attribute__((address_space(3))) unsigned int*)(Bs + base),
                    16, 0, 0);
            }
        }
    }

    // ---- per-lane f loads + z build (runs while W1 staging is in flight) ----
    const float* fp = fe + (n0 + w * 16 + r) * HDIM;
    uint4 zabs[NKC];
    uint4 zsig[4];                 // signed chunks kc=0..3 (pooling, oc-half)
    #pragma unroll
    for (int kc = 0; kc < NKC; kc++) {
        int pk = kc * 32 + g * 8;
        int hlf = (pk >= KHALF) ? 1 : 0;
        int col = pk - hlf * KHALF;
        const float* sp = hlf ? mvec : oc;
        bool v0 = col < HDIM, v1 = col + 4 < HDIM;
        float4 f0 = ld4c(fp + col, v0), f1 = ld4c(fp + col + 4, v1);
        float4 s0 = ld4c(sp + col, v0), s1 = ld4c(sp + col + 4, v1);
        uint4 u = pack_diff_u(f0, f1, s0, s1);
        if (kc < 4) zsig[kc] = u;
        u.x &= 0x7FFF7FFFu; u.y &= 0x7FFF7FFFu; u.z &= 0x7FFF7FFFu; u.w &= 0x7FFF7FFFu;
        zabs[kc] = u;
    }
    __syncthreads();   // drains vmcnt -> Bs ready

    // ---- GEMM: C[j][fact] = mfma(W1frag, |z|); C col = r = my fact; b1 in C-init ----
    float gacc = 0.f;
    #pragma unroll
    for (int jt = 0; jt < NJT; jt++) {
        int jb = jt * 16 + g * 4;
        bool jv = jb < HDIM;                       // group fully valid or fully dead
        float4 b1q = ld4c(b1 + jb, jv);
        float4 w2q = ld4c(W2 + jb, jv);
        f32x4 acc = {b1q.x, b1q.y, b1q.z, b1q.w};
        #pragma unroll
        for (int kc = 0; kc < NKC; kc++) {
            short8 av = __builtin_bit_cast(short8, Bs[(jt * NKC + kc) * 64 + lane]);
            acc = __builtin_amdgcn_mfma_f32_16x16x32_bf16(
                av, __builtin_bit_cast(short8, zabs[kc]), acc, 0, 0, 0);
        }
        gacc = fmaf(tanh_fast(acc[0]), w2q.x, gacc);
        gacc = fmaf(tanh_fast(acc[1]), w2q.y, gacc);
        gacc = fmaf(tanh_fast(acc[2]), w2q.z, gacc);
        gacc = fmaf(tanh_fast(acc[3]), w2q.w, gacc);
    }
    // combine the 4 g-group partials -> logit of fact (n0 + w*16 + r)
    gacc += __shfl_xor(gacc, 16);
    gacc += __shfl_xor(gacc, 32);
    float w_r = __expf(gacc);      // b2 dropped (softmax-invariant); |logit| <= sum|W2| ~ 8

    float s16 = row_reduce16(w_r);
    if (lane == 0) atomicAdd(&sS, s16);

    // ---- pooling from signed z regs: p[k] = sum_r w_r*(f-oc)[r][k] (oc-half only) ----
    float p[4][8];
    #pragma unroll
    for (int c = 0; c < 4; c++) {
        union { uint4 u; unsigned short us[8]; } uz; uz.u = zsig[c];
        #pragma unroll
        for (int e = 0; e < 8; e++) {
            float zf = __builtin_bit_cast(float, ((unsigned)uz.us[e]) << 16);
            p[c][e] = w_r * zf;
        }
    }
    #pragma unroll
    for (int c = 0; c < 4; c++)
        #pragma unroll
        for (int e = 0; e < 8; e++) p[c][e] = row_reduce16(p[c][e]);

    __syncthreads();   // ALL waves done reading Bs -> safe to alias pool2

    if (r == 0) {      // lanes g=0..3 write their oc-half slots (pk<112)
        #pragma unroll
        for (int c = 0; c < 4; c++) {
            int pk = c * 32 + g * 8;
            if (pk < KHALF) {
                float* dst = pool2 + w * KHALF + pk;
                *(float4*)(dst)     = make_float4(p[c][0], p[c][1], p[c][2], p[c][3]);
                *(float4*)(dst + 4) = make_float4(p[c][4], p[c][5], p[c][6], p[c][7]);
            }
        }
    }
    __syncthreads();

    // ---- block flush -> striped global accumulator ----
    int cp = (blockIdx.x & (NSTRIPE - 1)) * NCOPY;
    if (t < KHALF) {
        float a = 0.f;
        #pragma unroll
        for (int w8 = 0; w8 < 8; w8++) a += pool2[w8 * KHALF + t];
        if (t < HDIM) atomicAdd(&ws[WS_ACC + cp + t], a);
    }
    if (t == 0) atomicAdd(&ws[WS_ACC + cp + KHALF], sS);
}

// Tiny epilogue: c = oc + corr/S; gated update. One block.
__global__ __launch_bounds__(128) void k_final(
        const float* __restrict__ mvec,
        const float* __restrict__ oc,
        const float* __restrict__ W3,
        const float* __restrict__ b3,
        const float* __restrict__ ws,
        float* __restrict__ out) {
    __shared__ float vv[300];
    int t = threadIdx.x;
    float S = 0.f;
    #pragma unroll
    for (int i = 0; i < NSTRIPE; i++) S += ws[WS_ACC + i * NCOPY + KHALF];
    if (t < HDIM) {
        float corr = 0.f;
        #pragma unroll
        for (int i = 0; i < NSTRIPE; i++) corr += ws[WS_ACC + i * NCOPY + t];
        vv[t] = mvec[t];
        vv[HDIM + t] = oc[t] + corr / S;
        vv[2 * HDIM + t] = oc[t];
    }
    __syncthreads();
    if (t < HDIM) {
        float a = b3[t];
        const float* wr = W3 + t * 3 * HDIM;
        #pragma unroll 4
        for (int k = 0; k < 3 * HDIM; k++) a = fmaf(wr[k], vv[k], a);
        out[t] = fmaxf(a, 0.f);
    }
}

extern "C" void kernel_launch(void* const* d_in, const int* in_sizes, int n_in,
                              void* d_out, int out_size, void* d_ws, size_t ws_size,
                              hipStream_t stream) {
    const float* mvec = (const float*)d_in[0];
    const float* oh   = (const float*)d_in[1];
    const float* fe   = (const float*)d_in[2];
    const float* W1   = (const float*)d_in[3];
    const float* b1   = (const float*)d_in[4];
    const float* W2   = (const float*)d_in[5];
    const float* W3   = (const float*)d_in[7];
    const float* b3   = (const float*)d_in[8];
    float* ws  = (float*)d_ws;
    float* out = (float*)d_out;

    k_prep_b<<<15, 256, 0, stream>>>(W1, ws);
    k_logits<<<NBLK, NTHREADS, 0, stream>>>(fe, oh, mvec, b1, W2, ws);
    k_final<<<1, 128, 0, stream>>>(mvec, oh, W3, b3, ws, out);
}

// Round 13
// 79.068 us; speedup vs baseline: 2.7363x; 1.1819x over previous
//
#include <hip/hip_runtime.h>
#include <hip/hip_bf16.h>
#include <math.h>

#define HDIM 100
#define NFACT 262144
#define FPB   128             // facts per block (8 waves x 16)
#define NBLK  2048            // NFACT / FPB
#define NTHREADS 512

// K packed to 224: k in [0,112) -> (f - oc) (valid k<100), k in [112,224) -> (f - m)
// (valid k-112<100). Dead k ranges have W1-frag == 0 and z == 0. 112 % 8 == 0 so no
// 8-element MFMA k-group straddles the boundary.
#define KHALF 112
#define NJT 7                 // j-tiles of 16 (112 >= 100)
#define NKC 7                 // k-chunks of 32 (224)
#define NBFRAG (NJT * NKC * 64)   // 3136 uint4 = 50176 B

#define NCOPY 116             // accumulator stripe: corr[112] + S at [112]
#define NSTRIPE 4             // few stripes: 32 stripes caused 49 MB of L2-line thrash (R12)

using short8 = __attribute__((ext_vector_type(8))) short;
using f32x4  = __attribute__((ext_vector_type(4))) float;

// ---------------- ws float-offset layout ----------------
#define WS_B    0                 // 12544 floats (3136 uint4 W1-fragments, bf16 bits)
#define WS_ACC  12544             // NSTRIPE stripes x 116 floats (zeroed by k_prep_b)

__device__ __forceinline__ unsigned short f2bf(float x) {
    unsigned u = __builtin_bit_cast(unsigned, x);
    u += 0x7FFFu + ((u >> 16) & 1u);          // RNE round to bf16
    return (unsigned short)(u >> 16);
}

__device__ __forceinline__ float tanh_fast(float x) {
    float e = __expf(2.0f * x);
    return 1.0f - 2.0f / (1.0f + e);
}

// ---- Precompute W1 fragments (bf16), order [jt][kc][lane][8]; zero accumulators ----
// MFMA A operand: A[row=j][k]; per lane: j = jt*16 + (lane&15), k = kc*32 + (lane>>4)*8 + e.
__global__ __launch_bounds__(256) void k_prep_b(const float* __restrict__ W1,
                                                float* __restrict__ ws) {
    int tg = blockIdx.x * 256 + threadIdx.x;
    if (tg < NSTRIPE * NCOPY) ws[WS_ACC + tg] = 0.f;   // zero all stripes each call
    if (tg >= NBFRAG) return;
    int lane = tg & 63;
    int kc = (tg >> 6) % NKC;
    int jt = tg / (NKC * 64);
    int g = lane >> 4, r = lane & 15;
    int j = jt * 16 + r;
    unsigned short v[8];
    #pragma unroll
    for (int e = 0; e < 8; e++) {
        int kglob = kc * 32 + g * 8 + e;
        int half = (kglob >= KHALF) ? 1 : 0;
        int koff = kglob - half * KHALF;
        float x = 0.f;
        if (j < HDIM && koff < HDIM) x = W1[j * 200 + half * HDIM + koff];
        v[e] = f2bf(x);
    }
    uint4 d;
    d.x = (unsigned)v[0] | ((unsigned)v[1] << 16);
    d.y = (unsigned)v[2] | ((unsigned)v[3] << 16);
    d.z = (unsigned)v[4] | ((unsigned)v[5] << 16);
    d.w = (unsigned)v[6] | ((unsigned)v[7] << 16);
    ((uint4*)(ws + WS_B))[tg] = d;
}

__device__ __forceinline__ float4 ld4c(const float* p, bool ok) {
    float4 z = make_float4(0.f, 0.f, 0.f, 0.f);
    return ok ? *(const float4*)p : z;
}

__device__ __forceinline__ uint4 pack_diff_u(float4 a0, float4 a1,
                                             float4 b0, float4 b1) {
    union { __hip_bfloat16 h[8]; uint4 u; } u;
    u.h[0] = __float2bfloat16(a0.x - b0.x); u.h[1] = __float2bfloat16(a0.y - b0.y);
    u.h[2] = __float2bfloat16(a0.z - b0.z); u.h[3] = __float2bfloat16(a0.w - b0.w);
    u.h[4] = __float2bfloat16(a1.x - b1.x); u.h[5] = __float2bfloat16(a1.y - b1.y);
    u.h[6] = __float2bfloat16(a1.z - b1.z); u.h[7] = __float2bfloat16(a1.w - b1.w);
    return u.u;
}

// DPP row-rotate add (VALU pipe): x + rotate_within_16(x, N)
template<int CTRL>
__device__ __forceinline__ float dpp_radd(float x) {
    int y = __builtin_amdgcn_update_dpp(0, __builtin_bit_cast(int, x),
                                        CTRL, 0xF, 0xF, true);
    return x + __builtin_bit_cast(float, y);
}
__device__ __forceinline__ float row_reduce16(float x) {
    x = dpp_radd<0x121>(x);   // row_ror:1
    x = dpp_radd<0x122>(x);   // row_ror:2
    x = dpp_radd<0x124>(x);   // row_ror:4
    x = dpp_radd<0x128>(x);   // row_ror:8
    return x;                 // all 16 lanes of the row hold the row-sum
}

// One wave = 16 facts, all j. W1 table async-staged to LDS; pooling buffer
// ALIASES the W1 LDS after a post-GEMM barrier. oc|m and b1|W2 staged to
// zero-padded LDS (kills all per-lane cndmask-masked loads). ~52.1 KB LDS.
// launch_bounds min-wave = 4 (NOT 6/8: those cap VGPR and spill — R10/R11).
__global__ __launch_bounds__(NTHREADS, 4) void k_logits(
        const float* __restrict__ fe,
        const float* __restrict__ oc,
        const float* __restrict__ mvec,
        const float* __restrict__ b1,
        const float* __restrict__ W2,
        float* __restrict__ ws) {
    __shared__ __align__(16) char smem[NBFRAG * 16];   // 50176 B (table, then pool)
    __shared__ float cpad[2 * KHALF];                  // oc | m, zero-padded
    __shared__ float bw[2 * KHALF];                    // b1 | W2, zero-padded
    __shared__ float sS;
    uint4* Bs = (uint4*)smem;
    float* pool2 = (float*)smem;    // reused AFTER the post-GEMM barrier

    int t = threadIdx.x;
    int w = t >> 6, lane = t & 63, g = lane >> 4, r = lane & 15;
    long n0 = (long)blockIdx.x * FPB;

    if (t == 0) sS = 0.f;

    // ---- stage zero-padded params to LDS (one-time, coalesced) ----
    if (t < 2 * KHALF) {
        int half = t / KHALF, k = t % KHALF;
        cpad[t] = (k < HDIM) ? (half ? mvec[k] : oc[k]) : 0.f;
        bw[t]   = (k < HDIM) ? (half ? W2[k]   : b1[k]) : 0.f;
    }

    // ---- async stage W1 table: global -> LDS, width 16, linear layout ----
    {
        const uint4* Bg = (const uint4*)(ws + WS_B);
        #pragma unroll
        for (int i = 0; i < 7; i++) {
            int base = i * 512 + w * 64;          // wave-uniform
            if (base < NBFRAG) {
                __builtin_amdgcn_global_load_lds(
                    (const __attribute__((address_space(1))) unsigned int*)(Bg + base + lane),
                    (__attribute__((address_space(3))) unsigned int*)(Bs + base),
                    16, 0, 0);
            }
        }
    }

    // ---- per-lane f loads (unconditional; masked only in the final block) ----
    const float* fp = fe + (n0 + w * 16 + r) * HDIM;
    float4 f0c[NKC], f1c[NKC];
    if (blockIdx.x != NBLK - 1) {
        #pragma unroll
        for (int kc = 0; kc < NKC; kc++) {
            int pk = kc * 32 + g * 8;
            int col = (pk >= KHALF) ? (pk - KHALF) : pk;
            f0c[kc] = *(const float4*)(fp + col);       // may read past row end ->
            f1c[kc] = *(const float4*)(fp + col + 4);   // next row (finite; killed by W1=0)
        }
    } else {
        #pragma unroll
        for (int kc = 0; kc < NKC; kc++) {
            int pk = kc * 32 + g * 8;
            int col = (pk >= KHALF) ? (pk - KHALF) : pk;
            f0c[kc] = ld4c(fp + col, col < HDIM);
            f1c[kc] = ld4c(fp + col + 4, col + 4 < HDIM);
        }
    }
    __syncthreads();   // drains vmcnt -> Bs/cpad/bw ready

    // ---- z build from LDS-padded params (no masks) ----
    uint4 zabs[NKC];
    uint4 zsig[4];                 // signed chunks kc=0..3 (pooling, oc-half)
    #pragma unroll
    for (int kc = 0; kc < NKC; kc++) {
        int pk = kc * 32 + g * 8;
        float4 s0 = *(const float4*)(cpad + pk);
        float4 s1 = *(const float4*)(cpad + pk + 4);
        uint4 u = pack_diff_u(f0c[kc], f1c[kc], s0, s1);
        if (kc < 4) zsig[kc] = u;
        u.x &= 0x7FFF7FFFu; u.y &= 0x7FFF7FFFu; u.z &= 0x7FFF7FFFu; u.w &= 0x7FFF7FFFu;
        zabs[kc] = u;
    }

    // ---- GEMM: C[j][fact] = mfma(W1frag, |z|); C col = r = my fact; b1 in C-init ----
    float gacc = 0.f;
    #pragma unroll
    for (int jt = 0; jt < NJT; jt++) {
        int jb = jt * 16 + g * 4;
        float4 b1q = *(const float4*)(bw + jb);
        float4 w2q = *(const float4*)(bw + KHALF + jb);
        f32x4 acc = {b1q.x, b1q.y, b1q.z, b1q.w};
        #pragma unroll
        for (int kc = 0; kc < NKC; kc++) {
            short8 av = __builtin_bit_cast(short8, Bs[(jt * NKC + kc) * 64 + lane]);
            acc = __builtin_amdgcn_mfma_f32_16x16x32_bf16(
                av, __builtin_bit_cast(short8, zabs[kc]), acc, 0, 0, 0);
        }
        gacc = fmaf(tanh_fast(acc[0]), w2q.x, gacc);
        gacc = fmaf(tanh_fast(acc[1]), w2q.y, gacc);
        gacc = fmaf(tanh_fast(acc[2]), w2q.z, gacc);
        gacc = fmaf(tanh_fast(acc[3]), w2q.w, gacc);
    }
    // combine the 4 g-group partials -> logit of fact (n0 + w*16 + r)
    gacc += __shfl_xor(gacc, 16);
    gacc += __shfl_xor(gacc, 32);
    float w_r = __expf(gacc);      // b2 dropped (softmax-invariant); |logit| <= sum|W2| ~ 8

    float s16 = row_reduce16(w_r);
    if (lane == 0) atomicAdd(&sS, s16);

    // ---- pooling from signed z regs: p[k] = sum_r w_r*(f-oc)[r][k] (oc-half only) ----
    float p[4][8];
    #pragma unroll
    for (int c = 0; c < 4; c++) {
        union { uint4 u; unsigned short us[8]; } uz; uz.u = zsig[c];
        #pragma unroll
        for (int e = 0; e < 8; e++) {
            float zf = __builtin_bit_cast(float, ((unsigned)uz.us[e]) << 16);
            p[c][e] = w_r * zf;
        }
    }
    #pragma unroll
    for (int c = 0; c < 4; c++)
        #pragma unroll
        for (int e = 0; e < 8; e++) p[c][e] = row_reduce16(p[c][e]);

    __syncthreads();   // ALL waves done reading Bs -> safe to alias pool2

    if (r == 0) {      // lanes g=0..3 write their oc-half slots (pk<112)
        #pragma unroll
        for (int c = 0; c < 4; c++) {
            int pk = c * 32 + g * 8;
            if (pk < KHALF) {
                float* dst = pool2 + w * KHALF + pk;
                *(float4*)(dst)     = make_float4(p[c][0], p[c][1], p[c][2], p[c][3]);
                *(float4*)(dst + 4) = make_float4(p[c][4], p[c][5], p[c][6], p[c][7]);
            }
        }
    }
    __syncthreads();

    // ---- block flush -> striped global accumulator ----
    int cp = (blockIdx.x & (NSTRIPE - 1)) * NCOPY;
    if (t < KHALF) {
        float a = 0.f;
        #pragma unroll
        for (int w8 = 0; w8 < 8; w8++) a += pool2[w8 * KHALF + t];
        if (t < HDIM) atomicAdd(&ws[WS_ACC + cp + t], a);
    }
    if (t == 0) atomicAdd(&ws[WS_ACC + cp + KHALF], sS);
}

// Tiny epilogue: c = oc + corr/S; gated update. One block.
__global__ __launch_bounds__(128) void k_final(
        const float* __restrict__ mvec,
        const float* __restrict__ oc,
        const float* __restrict__ W3,
        const float* __restrict__ b3,
        const float* __restrict__ ws,
        float* __restrict__ out) {
    __shared__ float vv[300];
    int t = threadIdx.x;
    float S = 0.f;
    #pragma unroll
    for (int i = 0; i < NSTRIPE; i++) S += ws[WS_ACC + i * NCOPY + KHALF];
    if (t < HDIM) {
        float corr = 0.f;
        #pragma unroll
        for (int i = 0; i < NSTRIPE; i++) corr += ws[WS_ACC + i * NCOPY + t];
        vv[t] = mvec[t];
        vv[HDIM + t] = oc[t] + corr / S;
        vv[2 * HDIM + t] = oc[t];
    }
    __syncthreads();
    if (t < HDIM) {
        float a = b3[t];
        const float* wr = W3 + t * 3 * HDIM;
        #pragma unroll 4
        for (int k = 0; k < 3 * HDIM; k++) a = fmaf(wr[k], vv[k], a);
        out[t] = fmaxf(a, 0.f);
    }
}

extern "C" void kernel_launch(void* const* d_in, const int* in_sizes, int n_in,
                              void* d_out, int out_size, void* d_ws, size_t ws_size,
                              hipStream_t stream) {
    const float* mvec = (const float*)d_in[0];
    const float* oh   = (const float*)d_in[1];
    const float* fe   = (const float*)d_in[2];
    const float* W1   = (const float*)d_in[3];
    const float* b1   = (const float*)d_in[4];
    const float* W2   = (const float*)d_in[5];
    const float* W3   = (const float*)d_in[7];
    const float* b3   = (const float*)d_in[8];
    float* ws  = (float*)d_ws;
    float* out = (float*)d_out;

    k_prep_b<<<15, 256, 0, stream>>>(W1, ws);
    k_logits<<<NBLK, NTHREADS, 0, stream>>>(fe, oh, mvec, b1, W2, ws);
    k_final<<<1, 128, 0, stream>>>(mvec, oh, W3, b3, ws, out);
}